// Round 12
// baseline (31.212 us; speedup 1.0000x reference)
//
#include <hip/hip_runtime.h>

// SemiPool2d max-plus: out[b,c,p,q] = max_{i<7,j<7}( x[b,c,2p+i,2q+j] + w[c,i,j] )
// x: (8,64,224,224) f32, w: (1,64,7,7) f32, out: (8,64,109,109) f32
//
// Block = one channel (bc) x TWO 16-row output bands, double-buffered:
//   issue stage A (9 gload_lds/wave), issue stage B, vmcnt(9) [A done, B in
//   flight], barrier, compute A (B lands underneath), vmcnt(0), barrier,
//   store A, compute+store B.  Per-wave issue counts are uniform (518
//   chunks/wave = 8 full + 1 six-lane instr) so counted vmcnt is exact.
// Weights in SGPRs (bc blockIdx-derived). LDS dests lane-linear (m104).

#define HH 224
#define WW 224
#define HO 109
#define WO 109
#define CC 64
#define PBAND 16
#define NB 7
#define INROWS 37                  // 2*16+5
#define BANDF (INROWS*WW)          // 8288 floats = 33152 B per band
#define WCH 518                    // 16B chunks per wave = 8288/4/4 = 8*64+6

__global__ __launch_bounds__(256) void semipool_kernel(
    const float* __restrict__ x,
    const float* __restrict__ w,
    float* __restrict__ out)
{
    __shared__ float smem[2][BANDF];   // 66304 B -> 2 blocks/CU

    const int tid  = threadIdx.x;
    const int wv   = tid >> 6;
    const int lane = tid & 63;
    const int pairIdx = blockIdx.x >> 9;   // 0..3
    const int bc      = blockIdx.x & 511;  // scalar
    const int bandB   = pairIdx + 4;
    const bool hasB   = (bandB < NB);      // pairIdx < 3

    const int p0A = pairIdx * PBAND;                                   // 0,16,32,48
    int p0B = bandB * PBAND; if (p0B > HO - PBAND) p0B = HO - PBAND;   // 64,80,93

    const float* __restrict__ xc = x + bc * (HH * WW);

    // ---- stage band A: 9 vmem instrs per wave, lane-linear dests ----
    {
        const float* src = xc + (2 * p0A) * WW;
#pragma unroll
        for (int it = 0; it < 9; ++it) {
            int off = it * 64 + lane;
            if (off < WCH) {
                int c = wv * WCH + off;
                __builtin_amdgcn_global_load_lds(
                    (const __attribute__((address_space(1))) void*)(src + 4 * c),
                    (__attribute__((address_space(3))) void*)(&smem[0][4 * c]),
                    16, 0, 0);
            }
        }
    }
    // ---- stage band B into buf 1 (in flight during compute A) ----
    if (hasB) {
        const float* src = xc + (2 * p0B) * WW;
#pragma unroll
        for (int it = 0; it < 9; ++it) {
            int off = it * 64 + lane;
            if (off < WCH) {
                int c = wv * WCH + off;
                __builtin_amdgcn_global_load_lds(
                    (const __attribute__((address_space(1))) void*)(src + 4 * c),
                    (__attribute__((address_space(3))) void*)(&smem[1][4 * c]),
                    16, 0, 0);
            }
        }
    }

    // 49 channel weights -> SGPRs (uniform address; lgkmcnt path, not vmcnt)
    const float* __restrict__ wp = w + (bc & (CC - 1)) * 49;
    float wr[49];
#pragma unroll
    for (int k = 0; k < 49; ++k) wr[k] = wp[k];

    // own A-loads done (9 oldest of 18); B may remain outstanding
    if (hasB) asm volatile("s_waitcnt vmcnt(9)" ::: "memory");
    else      asm volatile("s_waitcnt vmcnt(0)" ::: "memory");
    __builtin_amdgcn_sched_barrier(0);
    __builtin_amdgcn_s_barrier();          // all waves' A staged
    __builtin_amdgcn_sched_barrier(0);

    int q = tid & 127; if (q > WO - 1) q = WO - 1;   // dups benign
    const int ph   = tid >> 7;
    const int colb = 2 * q;

    float accA[8], accB[8];

#define COMPUTE_BAND(BUF, ACC)                                            \
    do {                                                                  \
        _Pragma("unroll")                                                 \
        for (int a = 0; a < 8; ++a) ACC[a] = -1e30f;                      \
        _Pragma("unroll")                                                 \
        for (int r = 0; r < 21; ++r) {                                    \
            const float* lr = &smem[BUF][(16 * ph + r) * WW + colb];      \
            float xr[8];                                                  \
            _Pragma("unroll")                                             \
            for (int k = 0; k < 4; ++k) {                                 \
                float2 v = *reinterpret_cast<const float2*>(lr + 2 * k);  \
                xr[2 * k] = v.x; xr[2 * k + 1] = v.y;                     \
            }                                                             \
            _Pragma("unroll")                                             \
            for (int pp = 0; pp < 8; ++pp) {                              \
                int i = r - 2 * pp;                                       \
                if (i >= 0 && i < 7) {                                    \
                    float s0 = xr[0] + wr[i * 7 + 0];                     \
                    float s1 = xr[1] + wr[i * 7 + 1];                     \
                    float s2 = xr[2] + wr[i * 7 + 2];                     \
                    float s3 = xr[3] + wr[i * 7 + 3];                     \
                    float s4 = xr[4] + wr[i * 7 + 4];                     \
                    float s5 = xr[5] + wr[i * 7 + 5];                     \
                    float s6 = xr[6] + wr[i * 7 + 6];                     \
                    float t0 = fmaxf(fmaxf(s0, s1), s2);                  \
                    float t1 = fmaxf(fmaxf(s3, s4), s5);                  \
                    float t2 = fmaxf(fmaxf(t0, t1), s6);                  \
                    ACC[pp] = fmaxf(ACC[pp], t2);                         \
                }                                                         \
            }                                                             \
        }                                                                 \
    } while (0)

#define STORE_BAND(P0B, ACC)                                              \
    do {                                                                  \
        float* orow = out + (bc * HO + (P0B) + 8 * ph) * WO + q;          \
        _Pragma("unroll")                                                 \
        for (int pp = 0; pp < 8; ++pp) orow[pp * WO] = ACC[pp];           \
    } while (0)

    COMPUTE_BAND(0, accA);

    if (hasB) {
        asm volatile("s_waitcnt vmcnt(0)" ::: "memory");   // B staged (own)
        __builtin_amdgcn_sched_barrier(0);
        __builtin_amdgcn_s_barrier();                      // all waves' B staged
        __builtin_amdgcn_sched_barrier(0);
        STORE_BAND(p0A, accA);      // store latency hides under compute B
        COMPUTE_BAND(1, accB);
        STORE_BAND(p0B, accB);
    } else {
        STORE_BAND(p0A, accA);
    }
}

extern "C" void kernel_launch(void* const* d_in, const int* in_sizes, int n_in,
                              void* d_out, int out_size, void* d_ws, size_t ws_size,
                              hipStream_t stream) {
    const float* x = (const float*)d_in[0];
    const float* w = (const float*)d_in[1];
    float* out = (float*)d_out;

    int blocks = 4 * 512;                      // 2048: pairs {0,4},{1,5},{2,6},{3,-}
    semipool_kernel<<<blocks, 256, 0, stream>>>(x, w, out);
}

// Round 13
// 28.591 us; speedup vs baseline: 1.0917x; 1.0917x over previous
//
#include <hip/hip_runtime.h>

// SemiPool2d max-plus: out[b,c,p,q] = max_{i<7,j<7}( x[b,c,2p+i,2q+j] + w[c,i,j] )
// x: (8,64,224,224) f32, w: (1,64,7,7) f32, out: (8,64,109,109) f32
//
// Persistent double-buffered pipeline. 1024 blocks; block = half a channel =
// 7 bands of 8 output rows. Per tile: 21x224 f32 = 18816 B staged via
// global_load_lds (zero-VGPR DMA). LDS = 2 buffers = 37.6 KB -> 4 blocks/CU,
// 16 waves/CU. Loop: STAGE(t+1) -> vmcnt(5) [tile t done, t+1 in flight] ->
// barrier -> compute(t) -> store -> barrier. Per-wave stage = exactly 5 vmem
// instrs (294 chunks = 4*64+38; partial-exec 5th still counts) so the counted
// vmcnt is exact. Weights in SGPRs (bc blockIdx-derived).

#define HH 224
#define WW 224
#define HO 109
#define WO 109
#define CC 64
#define PBAND 8
#define NT 7                    // tiles (bands) per block
#define INROWS 21               // 2*8+5
#define BANDF (INROWS*WW)       // 4704 floats = 18816 B
#define WCHUNK 294              // 16B chunks per wave = 4704/4/4 = 4*64+38
#define STAGE_INSTR 5

__global__ __launch_bounds__(256) void semipool_kernel(
    const float* __restrict__ x,
    const float* __restrict__ w,
    float* __restrict__ out)
{
    __shared__ float smem[2][BANDF];   // 37632 B -> 4 blocks/CU

    const int tid  = threadIdx.x;
    const int wv   = tid >> 6;
    const int lane = tid & 63;
    const int half = blockIdx.x & 1;   // bands 0..6 or 7..13
    const int bc   = blockIdx.x >> 1;  // 0..511 (scalar)

    const float* __restrict__ xc = x + bc * (HH * WW);

    // 49 channel weights -> SGPRs (uniform address)
    const float* __restrict__ wp = w + (bc & (CC - 1)) * 49;
    float wr[49];
#pragma unroll
    for (int k = 0; k < 49; ++k) wr[k] = wp[k];

    int q = tid & 127; if (q > WO - 1) q = WO - 1;   // dups benign
    const int ph   = tid >> 7;                       // 0/1: rows p0+4ph..+3
    const int colb = 2 * q;

#define STAGE(BUF, P0)                                                        \
    do {                                                                      \
        const float* _src = xc + (2 * (P0)) * WW;                             \
        _Pragma("unroll")                                                     \
        for (int it = 0; it < STAGE_INSTR; ++it) {                            \
            int off = it * 64 + lane;                                         \
            if (off < WCHUNK) {                                               \
                int c = wv * WCHUNK + off;                                    \
                __builtin_amdgcn_global_load_lds(                             \
                    (const __attribute__((address_space(1))) void*)(_src + 4 * c), \
                    (__attribute__((address_space(3))) void*)(&smem[BUF][4 * c]),  \
                    16, 0, 0);                                                \
            }                                                                 \
        }                                                                     \
    } while (0)

    const int band0 = half * NT;
    {
        int p00 = band0 * PBAND; if (p00 > HO - PBAND) p00 = HO - PBAND;
        STAGE(0, p00);
    }

#pragma unroll 1
    for (int t = 0; t < NT; ++t) {
        const int cur = t & 1;
        int p0 = (band0 + t) * PBAND; if (p0 > HO - PBAND) p0 = HO - PBAND;

        if (t + 1 < NT) {
            int p0n = (band0 + t + 1) * PBAND;
            if (p0n > HO - PBAND) p0n = HO - PBAND;
            STAGE(cur ^ 1, p0n);
            asm volatile("s_waitcnt vmcnt(5)" ::: "memory");  // tile t done
        } else {
            asm volatile("s_waitcnt vmcnt(0)" ::: "memory");
        }
        __builtin_amdgcn_sched_barrier(0);
        __builtin_amdgcn_s_barrier();          // tile t visible to all waves
        __builtin_amdgcn_sched_barrier(0);

        // ---- compute 4 outputs (rows p0+4ph..+3, col q) from smem[cur] ----
        const float* __restrict__ sb = &smem[cur][0] + (8 * ph) * WW + colb;
        float acc[4];
#pragma unroll
        for (int a = 0; a < 4; ++a) acc[a] = -1e30f;

#pragma unroll
        for (int rr = 0; rr < 13; ++rr) {      // local input rows for thread
            const float* lr = sb + rr * WW;
            float xr[8];
#pragma unroll
            for (int k = 0; k < 4; ++k) {
                float2 v = *reinterpret_cast<const float2*>(lr + 2 * k);
                xr[2 * k]     = v.x;
                xr[2 * k + 1] = v.y;
            }
#pragma unroll
            for (int pp = 0; pp < 4; ++pp) {
                int i = rr - 2 * pp;           // compile-time after unroll
                if (i >= 0 && i < 7) {
                    float s0 = xr[0] + wr[i * 7 + 0];
                    float s1 = xr[1] + wr[i * 7 + 1];
                    float s2 = xr[2] + wr[i * 7 + 2];
                    float s3 = xr[3] + wr[i * 7 + 3];
                    float s4 = xr[4] + wr[i * 7 + 4];
                    float s5 = xr[5] + wr[i * 7 + 5];
                    float s6 = xr[6] + wr[i * 7 + 6];
                    float t0 = fmaxf(fmaxf(s0, s1), s2);   // v_max3
                    float t1 = fmaxf(fmaxf(s3, s4), s5);   // v_max3
                    float t2 = fmaxf(fmaxf(t0, t1), s6);   // v_max3
                    acc[pp] = fmaxf(acc[pp], t2);
                }
            }
        }

        float* __restrict__ orow = out + (bc * HO + p0 + 4 * ph) * WO + q;
#pragma unroll
        for (int pp = 0; pp < 4; ++pp)
            orow[pp * WO] = acc[pp];

        __builtin_amdgcn_sched_barrier(0);
        __builtin_amdgcn_s_barrier();          // all reads of smem[cur] done
        __builtin_amdgcn_sched_barrier(0);     // (tile t+2 will overwrite it)
    }
}

extern "C" void kernel_launch(void* const* d_in, const int* in_sizes, int n_in,
                              void* d_out, int out_size, void* d_ws, size_t ws_size,
                              hipStream_t stream) {
    const float* x = (const float*)d_in[0];
    const float* w = (const float*)d_in[1];
    float* out = (float*)d_out;

    semipool_kernel<<<1024, 256, 0, stream>>>(x, w, out);
}